// Round 5
// baseline (256.954 us; speedup 1.0000x reference)
//
#include <hip/hip_runtime.h>

#define B 256
#define N 512
#define M 512
#define BM (B * M)   // 131072
#define NM (N * M)   // 262144

// One ordinary kernel, 512 blocks x 512 threads, with a flag-based global
// barrier replacing the k_a | k_col dispatch boundary.
//
// Phase 1 (identical work/order to the proven round-0 k_a):
//   blk 0..15   : xT tiles   (unit u = blk*2+half, 32 units)
//   blk 16..47  : wT tiles   (64 units)
//   blk 48..63  : tT tiles   (32 units)
//   blk 64      : sum_x   blk 65: sum_w
//   blk 66..321 : relx units (512 units, 2 per block) -> px[z][m][n]
//   blk 322..511: no phase-1 work
// Barrier: producer release via atomicExch (RMW at coherence point);
//          consumer poll via atomicAdd(flag, 0) RMW — NOT a relaxed load,
//          which round 4 proved can spin ~180 us on a stale non-coherent
//          per-XCD L2 line. Wave 0 polls 8 flags/lane; __syncthreads()
//          releases the rest. Bounded spin: degradation, never a hang.
// Phase 2: round-0 k_col body verbatim (m = blockIdx.x).

#define HALF_BYTES 16640          // transpose half: 64*65*4; relx half: 12800
#define SMEM_BYTES 33280

__device__ __forceinline__ void tile_tr256(const float* __restrict__ src,
                                           float* __restrict__ dst,
                                           int R, int C, int r0, int c0,
                                           int tl, char* hbase) {
    float (*s)[65] = reinterpret_cast<float (*)[65]>(hbase);
    const int tx = tl & 63, q = tl >> 6;
    #pragma unroll
    for (int j = 0; j < 16; ++j) {
        int rl = q * 16 + j;
        s[rl][tx] = src[(r0 + rl) * C + c0 + tx];
    }
    __syncthreads();
    #pragma unroll
    for (int j = 0; j < 16; ++j) {
        int cl = q * 16 + j;
        dst[(c0 + cl) * R + r0 + tx] = s[tx][cl];
    }
}

__global__ __launch_bounds__(512, 4) void k_fused(
        const float* __restrict__ x, const float* __restrict__ w,
        const float* __restrict__ t,
        float* __restrict__ xT, float* __restrict__ wT, float* __restrict__ tT,
        float* __restrict__ sum_x, float* __restrict__ sum_w,
        float* __restrict__ px, int* __restrict__ flags,
        float* __restrict__ out) {
    __shared__ __align__(16) char smem[SMEM_BYTES];
    const int blk = blockIdx.x, tid = threadIdx.x;
    const int half = tid >> 8, tl = tid & 255;
    char* hbase = smem + half * HALF_BYTES;

    // ======================= phase 1 =======================
    if (blk < 16) {
        const int u = blk * 2 + half;                        // 0..31
        tile_tr256(x, xT, B, N, (u >> 3) * 64, (u & 7) * 64, tl, hbase);
    } else if (blk < 48) {
        const int u = (blk - 16) * 2 + half;                 // 0..63
        tile_tr256(w, wT, N, M, (u >> 3) * 64, (u & 7) * 64, tl, hbase);
    } else if (blk < 64) {
        const int u = (blk - 48) * 2 + half;                 // 0..31
        tile_tr256(t, tT, B, M, (u >> 3) * 64, (u & 7) * 64, tl, hbase);
    } else if (blk == 64) {
        const int i = tid;
        double a0 = 0, a1 = 0, a2 = 0, a3 = 0;
        for (int b = 0; b < B; b += 4) {
            a0 += (double)x[(b + 0) * N + i];
            a1 += (double)x[(b + 1) * N + i];
            a2 += (double)x[(b + 2) * N + i];
            a3 += (double)x[(b + 3) * N + i];
        }
        sum_x[i] = (float)((a0 + a1) + (a2 + a3));
    } else if (blk == 65) {
        const int mm = tid;
        double a0 = 0, a1 = 0, a2 = 0, a3 = 0;
        for (int n = 0; n < N; n += 4) {
            a0 += (double)w[(n + 0) * M + mm];
            a1 += (double)w[(n + 1) * M + mm];
            a2 += (double)w[(n + 2) * M + mm];
            a3 += (double)w[(n + 3) * M + mm];
        }
        sum_w[mm] = (float)((a0 + a1) + (a2 + a3));
    } else if (blk < 322) {
        // ---- relx unit rb = (blk-66)*2 + half (0..511), round-0 body ----
        const int rb  = (blk - 66) * 2 + half;
        const int z   = rb >> 7;
        const int rem = rb & 127;
        const int m0 = (rem & 7) * 64;
        const int n0 = (rem >> 3) * 32;
        const int tx = tl & 15, ty = tl >> 4;
        float (*s_t)[64] = reinterpret_cast<float (*)[64]>(hbase);          // 8192
        float (*s_x)[36] = reinterpret_cast<float (*)[36]>(hbase + 8192);   // 4608
        const int sr = tl >> 3, sc = tl & 7;
        float aA0 = 0.f, aA1 = 0.f, aA2 = 0.f, aA3 = 0.f;
        float aB0 = 0.f, aB1 = 0.f, aB2 = 0.f, aB3 = 0.f;
        const int nA = ty * 2, nB = nA + 1;
        for (int scnk = 0; scnk < 2; ++scnk) {
            const int bb = z * 64 + scnk * 32;
            __syncthreads();
            *(float4*)&s_t[sr][sc * 8]     = *(const float4*)&t[(bb + sr) * M + m0 + sc * 8];
            *(float4*)&s_t[sr][sc * 8 + 4] = *(const float4*)&t[(bb + sr) * M + m0 + sc * 8 + 4];
            *(float4*)&s_x[sr][sc * 4]     = *(const float4*)&x[(bb + sr) * N + n0 + sc * 4];
            __syncthreads();
            #pragma unroll 8
            for (int i = 0; i < 32; ++i) {           // b ascending: bit-identical
                float4 tv = *(const float4*)&s_t[i][tx * 4];
                float xA = s_x[i][nA], xB = s_x[i][nB];
                aA0 += fminf(xA, tv.x); aA1 += fminf(xA, tv.y);
                aA2 += fminf(xA, tv.z); aA3 += fminf(xA, tv.w);
                aB0 += fminf(xB, tv.x); aB1 += fminf(xB, tv.y);
                aB2 += fminf(xB, tv.z); aB3 += fminf(xB, tv.w);
            }
        }
        __syncthreads();
        float* so = &s_t[0][0];                      // [m-local*32 + n-local]
        so[(tx * 4 + 0) * 32 + nA] = aA0; so[(tx * 4 + 0) * 32 + nB] = aB0;
        so[(tx * 4 + 1) * 32 + nA] = aA1; so[(tx * 4 + 1) * 32 + nB] = aB1;
        so[(tx * 4 + 2) * 32 + nA] = aA2; so[(tx * 4 + 2) * 32 + nB] = aB2;
        so[(tx * 4 + 3) * 32 + nA] = aA3; so[(tx * 4 + 3) * 32 + nB] = aB3;
        __syncthreads();
        const int m_l = tl >> 2, n_l = (tl & 3) * 8;
        float* dst = &px[z * NM + (m0 + m_l) * N + n0 + n_l];
        *(float4*)&dst[0] = *(const float4*)&so[m_l * 32 + n_l];
        *(float4*)&dst[4] = *(const float4*)&so[m_l * 32 + n_l + 4];
    }

    // ======================= global barrier =======================
    const int lane = tid & 63, wid = tid >> 6;
    __threadfence();                                 // release: drain stores
    __syncthreads();                                 // whole block done
    if (tid == 0) atomicExch(&flags[blk], 1);        // RMW release at MALL
    if (wid == 0) {
        // RMW poll: atomicAdd(...,0) executes at the coherence point and
        // can never observe a stale per-XCD L2 line (round-4 lesson).
        #pragma unroll
        for (int j = 0; j < 8; ++j) {
            const int idx = lane * 8 + j;            // 64 lanes x 8 = 512 flags
            int spins = 0;
            while (atomicAdd(&flags[idx], 0) == 0) {
                __builtin_amdgcn_s_sleep(1);
                if (++spins > (1 << 20)) break;      // fail-safe: no hang
            }
        }
    }
    __threadfence();                                 // acquire
    __syncthreads();                                 // release waves 1..7

    // ======================= phase 2: k_col verbatim =======================
    const int m = blk;

    double* bsumI   = (double*)(smem);                    // 2048
    double* btot    = (double*)(smem + 2048);             // 32
    float*  worig   = (float*)(smem + 2080);              // 2048
    float*  pm      = (float*)(smem + 4128);              // 2048
    float*  wsrt    = (float*)(smem + 6176);              // 2048
    float*  srx_r   = (float*)(smem + 8224);              // 2048
    float*  srx_u   = (float*)(smem + 10272);             // 2048
    int*    srx_n   = (int*)(smem + 12320);               // 2048
    int*    cnt     = (int*)(smem + 14368);               // 1024
    int*    cbase   = (int*)(smem + 15392);               // 1024
    int*    cslot   = (int*)(smem + 16416);               // 1024
    int*    rcnt    = (int*)(smem + 17440);               // 1024
    int*    rbase   = (int*)(smem + 18464);               // 1024
    int*    rslot   = (int*)(smem + 19488);               // 1024
    int*    rbmax   = (int*)(smem + 20512);               // 1024
    float*  wtotmax = (float*)(smem + 21536);             // 32
    float (*red3)[8] = (float (*)[8])(smem + 21568);      // 96
    int*    ctot    = (int*)(smem + 21664);               // 16
    int*    rtot    = (int*)(smem + 21680);               // 16

    const float wv = wT[m * N + tid];
    float p = px[m * N + tid];
    p += px[NM + m * N + tid];
    p += px[2 * NM + m * N + tid];
    p += px[3 * NM + m * N + tid];
    const float rv = p / sum_x[tid];
    worig[tid] = wv;
    if (tid < 256) { cnt[tid] = 0; rcnt[tid] = 0; cslot[tid] = 0; rslot[tid] = 0; rbmax[tid] = 0; }

    float pmv = wv;
    #pragma unroll
    for (int off = 1; off < 64; off <<= 1) {
        float o = __shfl_up(pmv, off, 64);
        if (lane >= off) pmv = fmaxf(pmv, o);
    }
    if (lane == 63) wtotmax[wid] = pmv;
    float wmn = wv, rmn = rv, rmx = rv;
    #pragma unroll
    for (int off = 32; off > 0; off >>= 1) {
        wmn = fminf(wmn, __shfl_xor(wmn, off, 64));
        rmn = fminf(rmn, __shfl_xor(rmn, off, 64));
        rmx = fmaxf(rmx, __shfl_xor(rmx, off, 64));
    }
    if (lane == 0) { red3[0][wid] = wmn; red3[1][wid] = rmn; red3[2][wid] = rmx; }
    __syncthreads();                                           // (1)

    {
        float om = -1e30f;
        for (int j = 0; j < wid; ++j) om = fmaxf(om, wtotmax[j]);
        pm[tid] = fmaxf(pmv, om);
    }
    float wmin = red3[0][0], rmin = red3[1][0], rmax = red3[2][0], wmax = wtotmax[0];
    #pragma unroll
    for (int j = 1; j < 8; ++j) {
        wmin = fminf(wmin, red3[0][j]);
        rmin = fminf(rmin, red3[1][j]);
        rmax = fmaxf(rmax, red3[2][j]);
        wmax = fmaxf(wmax, wtotmax[j]);
    }

    const float wscale = 255.0f / fmaxf(wmax - wmin, 1e-30f);
    int wk = (int)((wv - wmin) * wscale);
    wk = wk < 0 ? 0 : (wk > 255 ? 255 : wk);
    atomicAdd(&cnt[wk], 1);
    const float rscale = 255.0f / fmaxf(rmax - rmin, 1e-30f);
    int rk;
    { int kv = (int)((rv - rmin) * rscale); kv = kv < 0 ? 0 : (kv > 255 ? 255 : kv); rk = 255 - kv; }
    atomicAdd(&rcnt[rk], 1);
    atomicMax(&rbmax[rk], __float_as_int(rv));                 // rv > 0
    __syncthreads();                                           // (2)

    int myc = (tid < 256) ? cnt[tid] : rcnt[tid - 256];
    int incl = myc;
    #pragma unroll
    for (int off = 1; off < 64; off <<= 1) {
        int o = __shfl_up(incl, off, 64);
        if (lane >= off) incl += o;
    }
    if (lane == 63) { if (wid < 4) ctot[wid] = incl; else rtot[wid - 4] = incl; }
    __syncthreads();                                           // (3)
    if (tid < 256) {
        int eo = 0;
        for (int j = 0; j < wid; ++j) eo += ctot[j];
        cbase[tid] = eo + incl - myc;
    } else {
        int eo = 0, w2 = wid - 4;
        for (int j = 0; j < w2; ++j) eo += rtot[j];
        rbase[tid - 256] = eo + incl - myc;
    }
    __syncthreads();                                           // (4)

    { int p1 = cbase[wk] + atomicAdd(&cslot[wk], 1); wsrt[p1] = wv; }
    { int p2 = rbase[rk] + atomicAdd(&rslot[rk], 1);
      srx_r[p2] = rv; srx_n[p2] = tid; srx_u[p2] = __int_as_float(rbmax[rk]); }
    __syncthreads();                                           // (5)

    double bincl = 0.0, mysum = 0.0;
    if (tid < 256) {
        int st = cbase[tid], e = st + cnt[tid];
        for (int i = st; i < e; ++i) mysum += (double)wsrt[i];
        bincl = mysum;
        #pragma unroll
        for (int off = 1; off < 64; off <<= 1) {
            double o = __shfl_up(bincl, off, 64);
            if (lane >= off) bincl += o;
        }
        if (lane == 63) btot[wid] = bincl;
    }
    __syncthreads();                                           // (6)
    if (tid < 256) {
        double eo = 0.0;
        for (int j = 0; j < wid; ++j) eo += btot[j];
        bsumI[tid] = eo + bincl;
    }
    __syncthreads();                                           // (7)

    if (tid < 256) {
        // ==== phase C: ind_w scan (waves 0-3) ====
        const int b = tid;
        float bv = -1.0f; int bi = 0;
        for (int i = 0; i < 512; ++i) {
            float u = srx_u[i];
            if (__ballot(u >= bv) == 0ULL) break;
            float r = srx_r[i];
            int   n = srx_n[i];
            float xv = xT[n * B + b];                // coalesced
            float v = fminf(xv, r);
            if (v > bv || (v == bv && n < bi)) { bv = v; bi = n; }
        }
        out[BM + b * M + m] = fminf(x[b * N + bi], worig[bi]);   // chosen_w
    } else {
        // ==== phase D: rel_w CDF + ind_x (waves 4-7) ====
        const int b = tid - 256;
        const float tbm = tT[m * B + b];
        float btf = (tbm - wmin) * wscale;
        int kk; double S;
        if (btf < 0.0f) { kk = 0; S = 0.0; }
        else {
            int bt = (int)btf; bt = bt > 255 ? 255 : bt;
            kk = cbase[bt];
            S = (bt > 0) ? bsumI[bt - 1] : 0.0;
            int e = cbase[bt] + cnt[bt];
            for (int i = cbase[bt]; i < e; ++i) {
                float v = wsrt[i];
                if (v < tbm) { ++kk; S += (double)v; }
            }
        }
        double rw = S + (double)tbm * (double)(512 - kk);
        float c = (float)rw / sum_w[m];
        float tgt = fminf(c, pm[511]);
        int lo = 0, hi = 511;
        while (lo < hi) { int mid = (lo + hi) >> 1; if (pm[mid] >= tgt) hi = mid; else lo = mid + 1; }
        const int ind = lo;
        out[b * M + m] = fminf(x[b * N + ind], worig[ind]);      // chosen_x
    }
}

extern "C" void kernel_launch(void* const* d_in, const int* in_sizes, int n_in,
                              void* d_out, int out_size, void* d_ws, size_t ws_size,
                              hipStream_t stream) {
    const float* x = (const float*)d_in[0];  // (B, N)
    const float* w = (const float*)d_in[1];  // (N, M)
    const float* t = (const float*)d_in[2];  // (B, M)
    float* out = (float*)d_out;

    float* ws = (float*)d_ws;
    float* xT    = ws;                 // 131072 floats
    float* wT    = ws + 131072;        // 262144
    float* tT    = ws + 393216;        // 131072
    float* sum_x = ws + 524288;        // 512
    float* sum_w = ws + 524800;        // 512
    float* px    = ws + 525312;        // 4*NM = 1048576
    int*   flags = (int*)(ws + 1573888); // 512 ints

    hipMemsetAsync(flags, 0, 512 * sizeof(int), stream);
    k_fused<<<512, 512, 0, stream>>>(x, w, t, xT, wT, tT,
                                     sum_x, sum_w, px, flags, out);
}

// Round 6
// 105.504 us; speedup vs baseline: 2.4355x; 2.4355x over previous
//
#include <hip/hip_runtime.h>

#define B 256
#define N 512
#define M 512
#define BM (B * M)   // 131072

// Two-dispatch structure (proven right: intra-kernel global barriers cost
// ~160us on MI355X regardless of poll method — rounds 4/5).
//
// k_a: 256 blocks x 256 threads.
//   blk 0..127  : relx tiles (m0 64-wide x n0 32-wide). Each block owns ALL
//                 4 z-chunks: p = z0; p+=z1; p+=z2; p+=z3 in registers
//                 (bit-identical to the old px-plane sum in k_col), computes
//                 sum_x for its 32 columns in-block (f64 chains by b&3,
//                 ascending — identical to old blk64), writes rv = p/sum_x
//                 directly: ONE 1MB plane instead of 4MB px + sum_x.
//   blk 128..159: xT tiles    blk 160..223: wT tiles    blk 224..255: tT
// k_col: 512 blocks x 512 threads — round-0 body with:
//   prologue: wv = wT[m*N+tid]; rv = rvp[m*N+tid]   (2 loads, no div)
//   sum_w computed in-block from worig (4 f64 chains by n&3 — round-3-proven)

__device__ __forceinline__ void tile_tr256(const float* __restrict__ src,
                                           float* __restrict__ dst,
                                           int R, int C, int r0, int c0, int tid) {
    __shared__ float s[64][65];
    const int tx = tid & 63, q = tid >> 6;
    #pragma unroll
    for (int j = 0; j < 16; ++j) {
        int rl = q * 16 + j;
        s[rl][tx] = src[(r0 + rl) * C + c0 + tx];
    }
    __syncthreads();
    #pragma unroll
    for (int j = 0; j < 16; ++j) {
        int cl = q * 16 + j;
        dst[(c0 + cl) * R + r0 + tx] = s[tx][cl];
    }
}

__global__ __launch_bounds__(256) void k_a(const float* __restrict__ x,
                                           const float* __restrict__ w,
                                           const float* __restrict__ t,
                                           float* __restrict__ xT,
                                           float* __restrict__ wT,
                                           float* __restrict__ tT,
                                           float* __restrict__ rvp) {
    const int blk = blockIdx.x, tid = threadIdx.x;
    if (blk < 128) {
        // ---- relx tile: all 4 z-chunks + sum_x + rv, one block ----
        const int m0 = (blk & 7) * 64;
        const int n0 = (blk >> 3) * 32;
        const int tx = tid & 15, ty = tid >> 4;      // tx: m-group, ty: n-group
        __shared__ float  s_t[32][64];               // [b-local][m-local]
        __shared__ float  s_x[32][36];               // [b-local][n-local]+pad
        __shared__ double sxc4[32][4];               // per-column f64 chains
        const int sr = tid >> 3, sc = tid & 7;
        const int nA = ty * 2, nB = nA + 1;
        float pA0, pA1, pA2, pA3, pB0, pB1, pB2, pB3;
        #pragma unroll
        for (int z = 0; z < 4; ++z) {                // z ascending
            float aA0 = 0.f, aA1 = 0.f, aA2 = 0.f, aA3 = 0.f;
            float aB0 = 0.f, aB1 = 0.f, aB2 = 0.f, aB3 = 0.f;
            for (int scnk = 0; scnk < 2; ++scnk) {
                const int bb = z * 64 + scnk * 32;
                __syncthreads();
                *(float4*)&s_t[sr][sc * 8]     = *(const float4*)&t[(bb + sr) * M + m0 + sc * 8];
                *(float4*)&s_t[sr][sc * 8 + 4] = *(const float4*)&t[(bb + sr) * M + m0 + sc * 8 + 4];
                *(float4*)&s_x[sr][sc * 4]     = *(const float4*)&x[(bb + sr) * N + n0 + sc * 4];
                __syncthreads();
                #pragma unroll 8
                for (int i = 0; i < 32; ++i) {       // b ascending: bit-identical
                    float4 tv = *(const float4*)&s_t[i][tx * 4];
                    float xA = s_x[i][nA], xB = s_x[i][nB];
                    aA0 += fminf(xA, tv.x); aA1 += fminf(xA, tv.y);
                    aA2 += fminf(xA, tv.z); aA3 += fminf(xA, tv.w);
                    aB0 += fminf(xB, tv.x); aB1 += fminf(xB, tv.y);
                    aB2 += fminf(xB, tv.z); aB3 += fminf(xB, tv.w);
                }
            }
            if (z == 0) {                            // p = z0; then p += z1..z3
                pA0 = aA0; pA1 = aA1; pA2 = aA2; pA3 = aA3;
                pB0 = aB0; pB1 = aB1; pB2 = aB2; pB3 = aB3;
            } else {
                pA0 += aA0; pA1 += aA1; pA2 += aA2; pA3 += aA3;
                pB0 += aB0; pB1 += aB1; pB2 += aB2; pB3 += aB3;
            }
        }
        // ---- sum_x: 128 threads, one f64 chain each (b = ch, ch+4, ...) ----
        if (tid < 128) {
            const int col = n0 + (tid >> 2), ch = tid & 3;
            double a = 0.0;
            for (int b = ch; b < B; b += 4) a += (double)x[b * N + col];
            sxc4[tid >> 2][ch] = a;
        }
        __syncthreads();                             // sxc4 ready; s_t reads done
        // identical combine per consumer -> identical bits
        const float sA = (float)((sxc4[nA][0] + sxc4[nA][1]) + (sxc4[nA][2] + sxc4[nA][3]));
        const float sB = (float)((sxc4[nB][0] + sxc4[nB][1]) + (sxc4[nB][2] + sxc4[nB][3]));
        // ---- stage 64x32 rv tile in LDS (reuse s_t), store coalesced ----
        float* so = &s_t[0][0];                      // [m-local*32 + n-local]
        so[(tx * 4 + 0) * 32 + nA] = pA0 / sA; so[(tx * 4 + 0) * 32 + nB] = pB0 / sB;
        so[(tx * 4 + 1) * 32 + nA] = pA1 / sA; so[(tx * 4 + 1) * 32 + nB] = pB1 / sB;
        so[(tx * 4 + 2) * 32 + nA] = pA2 / sA; so[(tx * 4 + 2) * 32 + nB] = pB2 / sB;
        so[(tx * 4 + 3) * 32 + nA] = pA3 / sA; so[(tx * 4 + 3) * 32 + nB] = pB3 / sB;
        __syncthreads();
        const int m_l = tid >> 2, n_l = (tid & 3) * 8;
        float* dst = &rvp[(m0 + m_l) * N + n0 + n_l];
        *(float4*)&dst[0] = *(const float4*)&so[m_l * 32 + n_l];
        *(float4*)&dst[4] = *(const float4*)&so[m_l * 32 + n_l + 4];
    } else if (blk < 160) {
        const int id = blk - 128;
        tile_tr256(x, xT, B, N, (id >> 3) * 64, (id & 7) * 64, tid);
    } else if (blk < 224) {
        const int id = blk - 160;
        tile_tr256(w, wT, N, M, (id >> 3) * 64, (id & 7) * 64, tid);
    } else {
        const int id = blk - 224;
        tile_tr256(t, tT, B, M, (id >> 3) * 64, (id & 7) * 64, tid);
    }
}

// ===========================================================================
// k_col: one block per column m (round-0 body; rv preloaded, sum_w in-block).
// ===========================================================================
__global__ __launch_bounds__(512) void k_col(
        const float* __restrict__ x, const float* __restrict__ xT,
        const float* __restrict__ wT, const float* __restrict__ tT,
        const float* __restrict__ rvp, float* __restrict__ out) {
    const int m = blockIdx.x, tid = threadIdx.x;
    const int lane = tid & 63, wid = tid >> 6;

    __shared__ float  worig[512], pm[512], wsrt[512];
    __shared__ float  srx_r[512], srx_u[512];
    __shared__ int    srx_n[512];
    __shared__ int    cnt[256], cbase[256], cslot[256];
    __shared__ int    rcnt[256], rbase[256], rslot[256], rbmax[256];
    __shared__ double bsumI[256];
    __shared__ double swpart[4];
    __shared__ float  wtotmax[8], red3[3][8];
    __shared__ int    ctot[4], rtot[4];
    __shared__ double btot[4];

    // ---- loads (rv bits identical: same p accumulation, same f64 sum_x) ----
    const float wv = wT[m * N + tid];
    const float rv = rvp[m * N + tid];
    worig[tid] = wv;
    if (tid < 256) { cnt[tid] = 0; rcnt[tid] = 0; cslot[tid] = 0; rslot[tid] = 0; rbmax[tid] = 0; }

    // ---- wave prefix-max (pm) + wave reductions (wmin,rmin,rmax) ----
    float pmv = wv;
    #pragma unroll
    for (int off = 1; off < 64; off <<= 1) {
        float o = __shfl_up(pmv, off, 64);
        if (lane >= off) pmv = fmaxf(pmv, o);
    }
    if (lane == 63) wtotmax[wid] = pmv;
    float wmn = wv, rmn = rv, rmx = rv;
    #pragma unroll
    for (int off = 32; off > 0; off >>= 1) {
        wmn = fminf(wmn, __shfl_xor(wmn, off, 64));
        rmn = fminf(rmn, __shfl_xor(rmn, off, 64));
        rmx = fmaxf(rmx, __shfl_xor(rmx, off, 64));
    }
    if (lane == 0) { red3[0][wid] = wmn; red3[1][wid] = rmn; red3[2][wid] = rmx; }
    __syncthreads();                                           // (1)

    // ---- sum_w f64 4-chains from worig (n&3 ascending; round-3-proven) ----
    if (tid < 4) {
        double a = 0.0;
        for (int n = tid; n < 512; n += 4) a += (double)worig[n];
        swpart[tid] = a;
    }

    {
        float om = -1e30f;
        for (int j = 0; j < wid; ++j) om = fmaxf(om, wtotmax[j]);
        pm[tid] = fmaxf(pmv, om);
    }
    float wmin = red3[0][0], rmin = red3[1][0], rmax = red3[2][0], wmax = wtotmax[0];
    #pragma unroll
    for (int j = 1; j < 8; ++j) {
        wmin = fminf(wmin, red3[0][j]);
        rmin = fminf(rmin, red3[1][j]);
        rmax = fmaxf(rmax, red3[2][j]);
        wmax = fmaxf(wmax, wtotmax[j]);
    }

    // ---- histograms ----
    const float wscale = 255.0f / fmaxf(wmax - wmin, 1e-30f);
    int wk = (int)((wv - wmin) * wscale);
    wk = wk < 0 ? 0 : (wk > 255 ? 255 : wk);
    atomicAdd(&cnt[wk], 1);
    const float rscale = 255.0f / fmaxf(rmax - rmin, 1e-30f);
    int rk;
    { int kv = (int)((rv - rmin) * rscale); kv = kv < 0 ? 0 : (kv > 255 ? 255 : kv); rk = 255 - kv; }
    atomicAdd(&rcnt[rk], 1);
    atomicMax(&rbmax[rk], __float_as_int(rv));                 // rv > 0
    __syncthreads();                                           // (2)

    // ---- both 256-prefix-sums concurrently: waves 0-3 cnt, waves 4-7 rcnt ----
    int myc = (tid < 256) ? cnt[tid] : rcnt[tid - 256];
    int incl = myc;
    #pragma unroll
    for (int off = 1; off < 64; off <<= 1) {
        int o = __shfl_up(incl, off, 64);
        if (lane >= off) incl += o;
    }
    if (lane == 63) { if (wid < 4) ctot[wid] = incl; else rtot[wid - 4] = incl; }
    __syncthreads();                                           // (3)
    if (tid < 256) {
        int eo = 0;
        for (int j = 0; j < wid; ++j) eo += ctot[j];
        cbase[tid] = eo + incl - myc;
    } else {
        int eo = 0, w2 = wid - 4;
        for (int j = 0; j < w2; ++j) eo += rtot[j];
        rbase[tid - 256] = eo + incl - myc;
    }
    __syncthreads();                                           // (4)

    // ---- scatter (bucket-ordered) ----
    { int p1 = cbase[wk] + atomicAdd(&cslot[wk], 1); wsrt[p1] = wv; }
    { int p2 = rbase[rk] + atomicAdd(&rslot[rk], 1);
      srx_r[p2] = rv; srx_n[p2] = tid; srx_u[p2] = __int_as_float(rbmax[rk]); }
    __syncthreads();                                           // (5)

    // ---- per-bucket f64 sums + 256-prefix (waves 0-3) ----
    double bincl = 0.0, mysum = 0.0;
    if (tid < 256) {
        int st = cbase[tid], e = st + cnt[tid];
        for (int i = st; i < e; ++i) mysum += (double)wsrt[i];
        bincl = mysum;
        #pragma unroll
        for (int off = 1; off < 64; off <<= 1) {
            double o = __shfl_up(bincl, off, 64);
            if (lane >= off) bincl += o;
        }
        if (lane == 63) btot[wid] = bincl;
    }
    __syncthreads();                                           // (6)
    if (tid < 256) {
        double eo = 0.0;
        for (int j = 0; j < wid; ++j) eo += btot[j];
        bsumI[tid] = eo + bincl;
    }
    __syncthreads();                                           // (7)

    if (tid < 256) {
        // ==== phase C: ind_w scan, descending-rel buckets (waves 0-3) ====
        const int b = tid;
        float bv = -1.0f; int bi = 0;
        for (int i = 0; i < 512; ++i) {
            float u = srx_u[i];                      // non-increasing bound
            if (__ballot(u >= bv) == 0ULL) break;
            float r = srx_r[i];
            int   n = srx_n[i];
            float xv = xT[n * B + b];                // coalesced
            float v = fminf(xv, r);
            if (v > bv || (v == bv && n < bi)) { bv = v; bi = n; }
        }
        out[BM + b * M + m] = fminf(x[b * N + bi], worig[bi]);   // chosen_w
    } else {
        // ==== phase D: rel_w CDF + ind_x (waves 4-7) ====
        const int b = tid - 256;
        const float tbm = tT[m * B + b];
        float btf = (tbm - wmin) * wscale;
        int kk; double S;
        if (btf < 0.0f) { kk = 0; S = 0.0; }
        else {
            int bt = (int)btf; bt = bt > 255 ? 255 : bt;
            kk = cbase[bt];
            S = (bt > 0) ? bsumI[bt - 1] : 0.0;
            int e = cbase[bt] + cnt[bt];
            for (int i = cbase[bt]; i < e; ++i) {
                float v = wsrt[i];
                if (v < tbm) { ++kk; S += (double)v; }
            }
        }
        double rw = S + (double)tbm * (double)(512 - kk);
        const float sw = (float)((swpart[0] + swpart[1]) + (swpart[2] + swpart[3]));
        float c = (float)rw / sw;
        float tgt = fminf(c, pm[511]);
        int lo = 0, hi = 511;
        while (lo < hi) { int mid = (lo + hi) >> 1; if (pm[mid] >= tgt) hi = mid; else lo = mid + 1; }
        const int ind = lo;
        out[b * M + m] = fminf(x[b * N + ind], worig[ind]);      // chosen_x
    }
}

extern "C" void kernel_launch(void* const* d_in, const int* in_sizes, int n_in,
                              void* d_out, int out_size, void* d_ws, size_t ws_size,
                              hipStream_t stream) {
    const float* x = (const float*)d_in[0];  // (B, N)
    const float* w = (const float*)d_in[1];  // (N, M)
    const float* t = (const float*)d_in[2];  // (B, M)
    float* out = (float*)d_out;

    float* ws = (float*)d_ws;
    float* xT  = ws;                 // 131072 floats
    float* wT  = ws + 131072;        // 262144
    float* tT  = ws + 393216;        // 131072
    float* rvp = ws + 524288;        // 262144  (rel_x plane, ~3 MB total)

    k_a  <<<256, 256, 0, stream>>>(x, w, t, xT, wT, tT, rvp);
    k_col<<<512, 512, 0, stream>>>(x, xT, wT, tT, rvp, out);
}

// Round 7
// 93.308 us; speedup vs baseline: 2.7538x; 1.1307x over previous
//
#include <hip/hip_runtime.h>

#define B 256
#define N 512
#define M 512
#define BM (B * M)   // 131072

// k_a: 640 blocks x 256 threads, all resident (LDS union 30.5 KB -> 5 blk/CU).
//   blk 0..31  : xT tiles   blk 32..95: wT   blk 96..127: tT  (short, first)
//   blk 128..639: relx tiles 32m x 16n. 256 threads = 4 z-groups (1 wave each)
//     computing the 4 independent 64-b chains IN PARALLEL (round-0 depth:
//     2 staged chunks/chain), then in-block combine p=(((z0+z1)+z2)+z3),
//     in-block sum_x f64 chains (b&3 ascending, (a0+a1)+(a2+a3)), and a
//     direct rv = p/sum_x write. Bit-identical to round-6's rvp (proven
//     absmax 0.0), with round-0's parallelism (round-6 lesson: serializing
//     z per block cost +15 us).
// k_col: round-6 body verbatim (rvp prologue + in-block sum_w; proven).

__device__ __forceinline__ void tile_tr256(const float* __restrict__ src,
                                           float* __restrict__ dst,
                                           int R, int C, int r0, int c0,
                                           int tid, char* smem) {
    float (*s)[65] = reinterpret_cast<float (*)[65]>(smem);
    const int tx = tid & 63, q = tid >> 6;
    #pragma unroll
    for (int j = 0; j < 16; ++j) {
        int rl = q * 16 + j;
        s[rl][tx] = src[(r0 + rl) * C + c0 + tx];
    }
    __syncthreads();
    #pragma unroll
    for (int j = 0; j < 16; ++j) {
        int cl = q * 16 + j;
        dst[(c0 + cl) * R + r0 + tx] = s[tx][cl];
    }
}

#define SMEM_BYTES 31232   // max(transpose 16640, relx 20480+10240+512)

__global__ __launch_bounds__(256) void k_a(const float* __restrict__ x,
                                           const float* __restrict__ w,
                                           const float* __restrict__ t,
                                           float* __restrict__ xT,
                                           float* __restrict__ wT,
                                           float* __restrict__ tT,
                                           float* __restrict__ rvp) {
    __shared__ __align__(16) char smem[SMEM_BYTES];
    const int blk = blockIdx.x, tid = threadIdx.x;
    if (blk < 32) {
        tile_tr256(x, xT, B, N, (blk >> 3) * 64, (blk & 7) * 64, tid, smem);
    } else if (blk < 96) {
        const int id = blk - 32;
        tile_tr256(w, wT, N, M, (id >> 3) * 64, (id & 7) * 64, tid, smem);
    } else if (blk < 128) {
        const int id = blk - 96;
        tile_tr256(t, tT, B, M, (id >> 3) * 64, (id & 7) * 64, tid, smem);
    } else {
        // ---- relx tile 32m x 16n, 4 parallel z-groups ----
        const int rb = blk - 128;                    // 0..511
        const int m0 = (rb & 15) * 32;               // 16 m-tiles
        const int n0 = (rb >> 4) * 16;               // 32 n-tiles
        // LDS union: S_T[4][32][40] | S_X[4][32][20] (PZ[4][32][17] overlays
        // S_X after the z-loop) | SX4[16][4] f64. Pads 40/20: 16B-aligned
        // rows, banks spread; PZ pad 17: 2-way max on scalar traffic.
        float  (*S_T)[32][40] = reinterpret_cast<float (*)[32][40]>(smem);
        float  (*S_X)[32][20] = reinterpret_cast<float (*)[32][20]>(smem + 20480);
        float  (*PZ)[32][17]  = reinterpret_cast<float (*)[32][17]>(smem + 20480);
        double (*SX4)[4]      = reinterpret_cast<double (*)[4]>(smem + 30720);
        const int zg = tid >> 6, tl = tid & 63;      // z-group == wave
        const int tx = tl & 7, ny = tl >> 3;         // tx: m-group, ny: n-group
        const int nA = ny * 2, nB = nA + 1;
        float aA0 = 0.f, aA1 = 0.f, aA2 = 0.f, aA3 = 0.f;
        float aB0 = 0.f, aB1 = 0.f, aB2 = 0.f, aB3 = 0.f;
        for (int s = 0; s < 2; ++s) {                // 2 staged chunks/chain
            __syncthreads();
            #pragma unroll
            for (int k = 0; k < 4; ++k) {            // stage t rows, coalesced
                const int f = k * 256 + tid;         // 1024 float4s
                const int row = f >> 3, c = f & 7;   // 8 lanes = 128B/row
                const int z = row >> 5, r = row & 31;
                *(float4*)&S_T[z][r][c * 4] =
                    *(const float4*)&t[(z * 64 + s * 32 + r) * M + m0 + c * 4];
            }
            #pragma unroll
            for (int k = 0; k < 2; ++k) {            // stage x rows
                const int f = k * 256 + tid;         // 512 float4s
                const int row = f >> 2, c = f & 3;   // 4 lanes = 64B/row
                const int z = row >> 5, r = row & 31;
                *(float4*)&S_X[z][r][c * 4] =
                    *(const float4*)&x[(z * 64 + s * 32 + r) * N + n0 + c * 4];
            }
            __syncthreads();
            #pragma unroll 8
            for (int i = 0; i < 32; ++i) {           // b ascending: bit-identical
                float4 tv = *(const float4*)&S_T[zg][i][tx * 4];
                float xA = S_X[zg][i][nA], xB = S_X[zg][i][nB];
                aA0 += fminf(xA, tv.x); aA1 += fminf(xA, tv.y);
                aA2 += fminf(xA, tv.z); aA3 += fminf(xA, tv.w);
                aB0 += fminf(xB, tv.x); aB1 += fminf(xB, tv.y);
                aB2 += fminf(xB, tv.z); aB3 += fminf(xB, tv.w);
            }
        }
        __syncthreads();                             // S_X dead -> PZ reuse ok
        // ---- z-partials to LDS ----
        PZ[zg][tx * 4 + 0][nA] = aA0; PZ[zg][tx * 4 + 0][nB] = aB0;
        PZ[zg][tx * 4 + 1][nA] = aA1; PZ[zg][tx * 4 + 1][nB] = aB1;
        PZ[zg][tx * 4 + 2][nA] = aA2; PZ[zg][tx * 4 + 2][nB] = aB2;
        PZ[zg][tx * 4 + 3][nA] = aA3; PZ[zg][tx * 4 + 3][nB] = aB3;
        // ---- sum_x: 64 threads, one f64 chain each (b = ch, ch+4, ...) ----
        if (tid < 64) {
            const int col = n0 + (tid >> 2), ch = tid & 3;
            double a = 0.0;
            for (int b = ch; b < B; b += 4) a += (double)x[b * N + col];
            SX4[tid >> 2][ch] = a;
        }
        __syncthreads();
        // ---- combine (((z0+z1)+z2)+z3), divide, write rv (2 outs/thread) ----
        {
            const int m_l = tid >> 3, np = (tid & 7) * 2;
            float p0 = PZ[0][m_l][np];
            p0 += PZ[1][m_l][np]; p0 += PZ[2][m_l][np]; p0 += PZ[3][m_l][np];
            float p1 = PZ[0][m_l][np + 1];
            p1 += PZ[1][m_l][np + 1]; p1 += PZ[2][m_l][np + 1]; p1 += PZ[3][m_l][np + 1];
            const float s0 = (float)((SX4[np][0] + SX4[np][1]) + (SX4[np][2] + SX4[np][3]));
            const float s1 = (float)((SX4[np + 1][0] + SX4[np + 1][1]) + (SX4[np + 1][2] + SX4[np + 1][3]));
            float2 rv2; rv2.x = p0 / s0; rv2.y = p1 / s1;
            *(float2*)&rvp[(m0 + m_l) * N + n0 + np] = rv2;
        }
    }
}

// ===========================================================================
// k_col: one block per column m (round-6 body verbatim; proven absmax 0.0).
// ===========================================================================
__global__ __launch_bounds__(512) void k_col(
        const float* __restrict__ x, const float* __restrict__ xT,
        const float* __restrict__ wT, const float* __restrict__ tT,
        const float* __restrict__ rvp, float* __restrict__ out) {
    const int m = blockIdx.x, tid = threadIdx.x;
    const int lane = tid & 63, wid = tid >> 6;

    __shared__ float  worig[512], pm[512], wsrt[512];
    __shared__ float  srx_r[512], srx_u[512];
    __shared__ int    srx_n[512];
    __shared__ int    cnt[256], cbase[256], cslot[256];
    __shared__ int    rcnt[256], rbase[256], rslot[256], rbmax[256];
    __shared__ double bsumI[256];
    __shared__ double swpart[4];
    __shared__ float  wtotmax[8], red3[3][8];
    __shared__ int    ctot[4], rtot[4];
    __shared__ double btot[4];

    // ---- loads (rv bits identical: same chains, same combine, same div) ----
    const float wv = wT[m * N + tid];
    const float rv = rvp[m * N + tid];
    worig[tid] = wv;
    if (tid < 256) { cnt[tid] = 0; rcnt[tid] = 0; cslot[tid] = 0; rslot[tid] = 0; rbmax[tid] = 0; }

    // ---- wave prefix-max (pm) + wave reductions (wmin,rmin,rmax) ----
    float pmv = wv;
    #pragma unroll
    for (int off = 1; off < 64; off <<= 1) {
        float o = __shfl_up(pmv, off, 64);
        if (lane >= off) pmv = fmaxf(pmv, o);
    }
    if (lane == 63) wtotmax[wid] = pmv;
    float wmn = wv, rmn = rv, rmx = rv;
    #pragma unroll
    for (int off = 32; off > 0; off >>= 1) {
        wmn = fminf(wmn, __shfl_xor(wmn, off, 64));
        rmn = fminf(rmn, __shfl_xor(rmn, off, 64));
        rmx = fmaxf(rmx, __shfl_xor(rmx, off, 64));
    }
    if (lane == 0) { red3[0][wid] = wmn; red3[1][wid] = rmn; red3[2][wid] = rmx; }
    __syncthreads();                                           // (1)

    // ---- sum_w f64 4-chains from worig (n&3 ascending; round-6-proven) ----
    if (tid < 4) {
        double a = 0.0;
        for (int n = tid; n < 512; n += 4) a += (double)worig[n];
        swpart[tid] = a;
    }

    {
        float om = -1e30f;
        for (int j = 0; j < wid; ++j) om = fmaxf(om, wtotmax[j]);
        pm[tid] = fmaxf(pmv, om);
    }
    float wmin = red3[0][0], rmin = red3[1][0], rmax = red3[2][0], wmax = wtotmax[0];
    #pragma unroll
    for (int j = 1; j < 8; ++j) {
        wmin = fminf(wmin, red3[0][j]);
        rmin = fminf(rmin, red3[1][j]);
        rmax = fmaxf(rmax, red3[2][j]);
        wmax = fmaxf(wmax, wtotmax[j]);
    }

    // ---- histograms ----
    const float wscale = 255.0f / fmaxf(wmax - wmin, 1e-30f);
    int wk = (int)((wv - wmin) * wscale);
    wk = wk < 0 ? 0 : (wk > 255 ? 255 : wk);
    atomicAdd(&cnt[wk], 1);
    const float rscale = 255.0f / fmaxf(rmax - rmin, 1e-30f);
    int rk;
    { int kv = (int)((rv - rmin) * rscale); kv = kv < 0 ? 0 : (kv > 255 ? 255 : kv); rk = 255 - kv; }
    atomicAdd(&rcnt[rk], 1);
    atomicMax(&rbmax[rk], __float_as_int(rv));                 // rv > 0
    __syncthreads();                                           // (2)

    // ---- both 256-prefix-sums concurrently: waves 0-3 cnt, waves 4-7 rcnt ----
    int myc = (tid < 256) ? cnt[tid] : rcnt[tid - 256];
    int incl = myc;
    #pragma unroll
    for (int off = 1; off < 64; off <<= 1) {
        int o = __shfl_up(incl, off, 64);
        if (lane >= off) incl += o;
    }
    if (lane == 63) { if (wid < 4) ctot[wid] = incl; else rtot[wid - 4] = incl; }
    __syncthreads();                                           // (3)
    if (tid < 256) {
        int eo = 0;
        for (int j = 0; j < wid; ++j) eo += ctot[j];
        cbase[tid] = eo + incl - myc;
    } else {
        int eo = 0, w2 = wid - 4;
        for (int j = 0; j < w2; ++j) eo += rtot[j];
        rbase[tid - 256] = eo + incl - myc;
    }
    __syncthreads();                                           // (4)

    // ---- scatter (bucket-ordered) ----
    { int p1 = cbase[wk] + atomicAdd(&cslot[wk], 1); wsrt[p1] = wv; }
    { int p2 = rbase[rk] + atomicAdd(&rslot[rk], 1);
      srx_r[p2] = rv; srx_n[p2] = tid; srx_u[p2] = __int_as_float(rbmax[rk]); }
    __syncthreads();                                           // (5)

    // ---- per-bucket f64 sums + 256-prefix (waves 0-3) ----
    double bincl = 0.0, mysum = 0.0;
    if (tid < 256) {
        int st = cbase[tid], e = st + cnt[tid];
        for (int i = st; i < e; ++i) mysum += (double)wsrt[i];
        bincl = mysum;
        #pragma unroll
        for (int off = 1; off < 64; off <<= 1) {
            double o = __shfl_up(bincl, off, 64);
            if (lane >= off) bincl += o;
        }
        if (lane == 63) btot[wid] = bincl;
    }
    __syncthreads();                                           // (6)
    if (tid < 256) {
        double eo = 0.0;
        for (int j = 0; j < wid; ++j) eo += btot[j];
        bsumI[tid] = eo + bincl;
    }
    __syncthreads();                                           // (7)

    if (tid < 256) {
        // ==== phase C: ind_w scan, descending-rel buckets (waves 0-3) ====
        const int b = tid;
        float bv = -1.0f; int bi = 0;
        for (int i = 0; i < 512; ++i) {
            float u = srx_u[i];                      // non-increasing bound
            if (__ballot(u >= bv) == 0ULL) break;
            float r = srx_r[i];
            int   n = srx_n[i];
            float xv = xT[n * B + b];                // coalesced
            float v = fminf(xv, r);
            if (v > bv || (v == bv && n < bi)) { bv = v; bi = n; }
        }
        out[BM + b * M + m] = fminf(x[b * N + bi], worig[bi]);   // chosen_w
    } else {
        // ==== phase D: rel_w CDF + ind_x (waves 4-7) ====
        const int b = tid - 256;
        const float tbm = tT[m * B + b];
        float btf = (tbm - wmin) * wscale;
        int kk; double S;
        if (btf < 0.0f) { kk = 0; S = 0.0; }
        else {
            int bt = (int)btf; bt = bt > 255 ? 255 : bt;
            kk = cbase[bt];
            S = (bt > 0) ? bsumI[bt - 1] : 0.0;
            int e = cbase[bt] + cnt[bt];
            for (int i = cbase[bt]; i < e; ++i) {
                float v = wsrt[i];
                if (v < tbm) { ++kk; S += (double)v; }
            }
        }
        double rw = S + (double)tbm * (double)(512 - kk);
        const float sw = (float)((swpart[0] + swpart[1]) + (swpart[2] + swpart[3]));
        float c = (float)rw / sw;
        float tgt = fminf(c, pm[511]);
        int lo = 0, hi = 511;
        while (lo < hi) { int mid = (lo + hi) >> 1; if (pm[mid] >= tgt) hi = mid; else lo = mid + 1; }
        const int ind = lo;
        out[b * M + m] = fminf(x[b * N + ind], worig[ind]);      // chosen_x
    }
}

extern "C" void kernel_launch(void* const* d_in, const int* in_sizes, int n_in,
                              void* d_out, int out_size, void* d_ws, size_t ws_size,
                              hipStream_t stream) {
    const float* x = (const float*)d_in[0];  // (B, N)
    const float* w = (const float*)d_in[1];  // (N, M)
    const float* t = (const float*)d_in[2];  // (B, M)
    float* out = (float*)d_out;

    float* ws = (float*)d_ws;
    float* xT  = ws;                 // 131072 floats
    float* wT  = ws + 131072;        // 262144
    float* tT  = ws + 393216;        // 131072
    float* rvp = ws + 524288;        // 262144  (rel_x plane; ~3 MB total)

    k_a  <<<640, 256, 0, stream>>>(x, w, t, xT, wT, tT, rvp);
    k_col<<<512, 512, 0, stream>>>(x, xT, wT, tT, rvp, out);
}

// Round 8
// 91.362 us; speedup vs baseline: 2.8125x; 1.0213x over previous
//
#include <hip/hip_runtime.h>

#define B 256
#define N 512
#define M 512
#define BM (B * M)   // 131072
#define NM (N * M)   // 262144

// Round-0 structure exactly (proven 90.0us, absmax 0.0), with ONE change:
// relx blocks use 64m x 64n tiles, 4m x 4n per thread (2 ds_read_b128 ->
// 16 outputs/iter instead of 3 reads -> 8), z-chunk per block preserved.
// 256 relx blocks instead of 512; px written from registers (no restage).
// Everything else (transposes, sum blocks, k_col) is round-0 verbatim.

__device__ __forceinline__ void tile_tr256(const float* __restrict__ src,
                                           float* __restrict__ dst,
                                           int R, int C, int r0, int c0, int tid) {
    __shared__ float s[64][65];
    const int tx = tid & 63, q = tid >> 6;
    #pragma unroll
    for (int j = 0; j < 16; ++j) {
        int rl = q * 16 + j;
        s[rl][tx] = src[(r0 + rl) * C + c0 + tx];
    }
    __syncthreads();
    #pragma unroll
    for (int j = 0; j < 16; ++j) {
        int cl = q * 16 + j;
        dst[(c0 + cl) * R + r0 + tx] = s[tx][cl];
    }
}

__global__ __launch_bounds__(256) void k_a(const float* __restrict__ x,
                                           const float* __restrict__ w,
                                           const float* __restrict__ t,
                                           float* __restrict__ xT,
                                           float* __restrict__ wT,
                                           float* __restrict__ tT,
                                           float* __restrict__ sum_x,
                                           float* __restrict__ sum_w,
                                           float* __restrict__ px) {
    const int blk = blockIdx.x, tid = threadIdx.x;
    if (blk < 32) {
        tile_tr256(x, xT, B, N, (blk >> 3) * 64, (blk & 7) * 64, tid);
    } else if (blk < 96) {
        int id = blk - 32;
        tile_tr256(w, wT, N, M, (id >> 3) * 64, (id & 7) * 64, tid);
    } else if (blk < 128) {
        int id = blk - 96;
        tile_tr256(t, tT, B, M, (id >> 3) * 64, (id & 7) * 64, tid);
    } else if (blk < 130) {
        const int i = (blk - 128) * 256 + tid;       // one element per thread
        double a0 = 0, a1 = 0, a2 = 0, a3 = 0;
        for (int b = 0; b < B; b += 4) {
            a0 += (double)x[(b + 0) * N + i];
            a1 += (double)x[(b + 1) * N + i];
            a2 += (double)x[(b + 2) * N + i];
            a3 += (double)x[(b + 3) * N + i];
        }
        sum_x[i] = (float)((a0 + a1) + (a2 + a3));
    } else if (blk < 132) {
        const int mm = (blk - 130) * 256 + tid;
        double a0 = 0, a1 = 0, a2 = 0, a3 = 0;
        for (int n = 0; n < N; n += 4) {
            a0 += (double)w[(n + 0) * M + mm];
            a1 += (double)w[(n + 1) * M + mm];
            a2 += (double)w[(n + 2) * M + mm];
            a3 += (double)w[(n + 3) * M + mm];
        }
        sum_w[mm] = (float)((a0 + a1) + (a2 + a3));
    } else {
        // ---- relxA: tile 64m x 64n, thread = 4m x 4n, z-chunk of 64 b ----
        const int rb  = blk - 132;                   // 0..255
        const int z   = rb >> 6;
        const int rem = rb & 63;
        const int m0 = (rem & 7) * 64;
        const int n0 = (rem >> 3) * 64;
        const int tx = tid & 15, ty = tid >> 4;      // tx: m-group, ty: n-group
        __shared__ float s_t[32][64];                // [b-local][m-local]
        __shared__ float s_x[32][64];                // [b-local][n-local]
        float a00 = 0.f, a01 = 0.f, a02 = 0.f, a03 = 0.f;
        float a10 = 0.f, a11 = 0.f, a12 = 0.f, a13 = 0.f;
        float a20 = 0.f, a21 = 0.f, a22 = 0.f, a23 = 0.f;
        float a30 = 0.f, a31 = 0.f, a32 = 0.f, a33 = 0.f;
        for (int scnk = 0; scnk < 2; ++scnk) {
            const int bb = z * 64 + scnk * 32;
            __syncthreads();
            #pragma unroll
            for (int k = 0; k < 2; ++k) {            // 512 float4s each array
                const int f = k * 256 + tid;
                const int row = f >> 4, c = (f & 15) * 4;
                *(float4*)&s_t[row][c] = *(const float4*)&t[(bb + row) * M + m0 + c];
                *(float4*)&s_x[row][c] = *(const float4*)&x[(bb + row) * N + n0 + c];
            }
            __syncthreads();
            #pragma unroll 8
            for (int i = 0; i < 32; ++i) {           // b ascending: bit-identical
                const float4 tv = *(const float4*)&s_t[i][tx * 4];
                const float4 xv = *(const float4*)&s_x[i][ty * 4];
                a00 += fminf(xv.x, tv.x); a01 += fminf(xv.y, tv.x);
                a02 += fminf(xv.z, tv.x); a03 += fminf(xv.w, tv.x);
                a10 += fminf(xv.x, tv.y); a11 += fminf(xv.y, tv.y);
                a12 += fminf(xv.z, tv.y); a13 += fminf(xv.w, tv.y);
                a20 += fminf(xv.x, tv.z); a21 += fminf(xv.y, tv.z);
                a22 += fminf(xv.z, tv.z); a23 += fminf(xv.w, tv.z);
                a30 += fminf(xv.x, tv.w); a31 += fminf(xv.y, tv.w);
                a32 += fminf(xv.z, tv.w); a33 += fminf(xv.w, tv.w);
            }
        }
        // direct register->px write: 4 rows x one float4 (64B segments, L2)
        float* base = &px[z * NM + (m0 + tx * 4) * N + n0 + ty * 4];
        { float4 o; o.x = a00; o.y = a01; o.z = a02; o.w = a03; *(float4*)&base[0 * N] = o; }
        { float4 o; o.x = a10; o.y = a11; o.z = a12; o.w = a13; *(float4*)&base[1 * N] = o; }
        { float4 o; o.x = a20; o.y = a21; o.z = a22; o.w = a23; *(float4*)&base[2 * N] = o; }
        { float4 o; o.x = a30; o.y = a31; o.z = a32; o.w = a33; *(float4*)&base[3 * N] = o; }
    }
}

// ===========================================================================
// k_col: one block per column m (round-0 body verbatim; proven absmax 0.0).
// ===========================================================================
__global__ __launch_bounds__(512) void k_col(
        const float* __restrict__ x, const float* __restrict__ xT,
        const float* __restrict__ wT, const float* __restrict__ tT,
        const float* __restrict__ px, const float* __restrict__ sum_x,
        const float* __restrict__ sum_w, float* __restrict__ out) {
    const int m = blockIdx.x, tid = threadIdx.x;
    const int lane = tid & 63, wid = tid >> 6;

    __shared__ float  worig[512], pm[512], wsrt[512];
    __shared__ float  srx_r[512], srx_u[512];
    __shared__ int    srx_n[512];
    __shared__ int    cnt[256], cbase[256], cslot[256];
    __shared__ int    rcnt[256], rbase[256], rslot[256], rbmax[256];
    __shared__ double bsumI[256];
    __shared__ float  wtotmax[8], red3[3][8];
    __shared__ int    ctot[4], rtot[4];
    __shared__ double btot[4];

    // ---- loads (bit-identical rv expression) ----
    const float wv = wT[m * N + tid];
    float p = px[m * N + tid];
    p += px[NM + m * N + tid];
    p += px[2 * NM + m * N + tid];
    p += px[3 * NM + m * N + tid];
    const float rv = p / sum_x[tid];
    worig[tid] = wv;
    if (tid < 256) { cnt[tid] = 0; rcnt[tid] = 0; cslot[tid] = 0; rslot[tid] = 0; rbmax[tid] = 0; }

    // ---- wave prefix-max (pm) + wave reductions (wmin,rmin,rmax) ----
    float pmv = wv;
    #pragma unroll
    for (int off = 1; off < 64; off <<= 1) {
        float o = __shfl_up(pmv, off, 64);
        if (lane >= off) pmv = fmaxf(pmv, o);
    }
    if (lane == 63) wtotmax[wid] = pmv;
    float wmn = wv, rmn = rv, rmx = rv;
    #pragma unroll
    for (int off = 32; off > 0; off >>= 1) {
        wmn = fminf(wmn, __shfl_xor(wmn, off, 64));
        rmn = fminf(rmn, __shfl_xor(rmn, off, 64));
        rmx = fmaxf(rmx, __shfl_xor(rmx, off, 64));
    }
    if (lane == 0) { red3[0][wid] = wmn; red3[1][wid] = rmn; red3[2][wid] = rmx; }
    __syncthreads();                                           // (1)

    {
        float om = -1e30f;
        for (int j = 0; j < wid; ++j) om = fmaxf(om, wtotmax[j]);
        pm[tid] = fmaxf(pmv, om);
    }
    float wmin = red3[0][0], rmin = red3[1][0], rmax = red3[2][0], wmax = wtotmax[0];
    #pragma unroll
    for (int j = 1; j < 8; ++j) {
        wmin = fminf(wmin, red3[0][j]);
        rmin = fminf(rmin, red3[1][j]);
        rmax = fmaxf(rmax, red3[2][j]);
        wmax = fmaxf(wmax, wtotmax[j]);
    }

    // ---- histograms ----
    const float wscale = 255.0f / fmaxf(wmax - wmin, 1e-30f);
    int wk = (int)((wv - wmin) * wscale);
    wk = wk < 0 ? 0 : (wk > 255 ? 255 : wk);
    atomicAdd(&cnt[wk], 1);
    const float rscale = 255.0f / fmaxf(rmax - rmin, 1e-30f);
    int rk;
    { int kv = (int)((rv - rmin) * rscale); kv = kv < 0 ? 0 : (kv > 255 ? 255 : kv); rk = 255 - kv; }
    atomicAdd(&rcnt[rk], 1);
    atomicMax(&rbmax[rk], __float_as_int(rv));                 // rv > 0
    __syncthreads();                                           // (2)

    // ---- both 256-prefix-sums concurrently: waves 0-3 cnt, waves 4-7 rcnt ----
    int myc = (tid < 256) ? cnt[tid] : rcnt[tid - 256];
    int incl = myc;
    #pragma unroll
    for (int off = 1; off < 64; off <<= 1) {
        int o = __shfl_up(incl, off, 64);
        if (lane >= off) incl += o;
    }
    if (lane == 63) { if (wid < 4) ctot[wid] = incl; else rtot[wid - 4] = incl; }
    __syncthreads();                                           // (3)
    if (tid < 256) {
        int eo = 0;
        for (int j = 0; j < wid; ++j) eo += ctot[j];
        cbase[tid] = eo + incl - myc;
    } else {
        int eo = 0, w2 = wid - 4;
        for (int j = 0; j < w2; ++j) eo += rtot[j];
        rbase[tid - 256] = eo + incl - myc;
    }
    __syncthreads();                                           // (4)

    // ---- scatter (bucket-ordered) ----
    { int p1 = cbase[wk] + atomicAdd(&cslot[wk], 1); wsrt[p1] = wv; }
    { int p2 = rbase[rk] + atomicAdd(&rslot[rk], 1);
      srx_r[p2] = rv; srx_n[p2] = tid; srx_u[p2] = __int_as_float(rbmax[rk]); }
    __syncthreads();                                           // (5)

    // ---- per-bucket f64 sums + 256-prefix (waves 0-3) ----
    double bincl = 0.0, mysum = 0.0;
    if (tid < 256) {
        int st = cbase[tid], e = st + cnt[tid];
        for (int i = st; i < e; ++i) mysum += (double)wsrt[i];
        bincl = mysum;
        #pragma unroll
        for (int off = 1; off < 64; off <<= 1) {
            double o = __shfl_up(bincl, off, 64);
            if (lane >= off) bincl += o;
        }
        if (lane == 63) btot[wid] = bincl;
    }
    __syncthreads();                                           // (6)
    if (tid < 256) {
        double eo = 0.0;
        for (int j = 0; j < wid; ++j) eo += btot[j];
        bsumI[tid] = eo + bincl;
    }
    __syncthreads();                                           // (7)

    if (tid < 256) {
        // ==== phase C: ind_w scan, descending-rel buckets (waves 0-3) ====
        const int b = tid;
        float bv = -1.0f; int bi = 0;
        for (int i = 0; i < 512; ++i) {
            float u = srx_u[i];                      // non-increasing bound
            if (__ballot(u >= bv) == 0ULL) break;
            float r = srx_r[i];
            int   n = srx_n[i];
            float xv = xT[n * B + b];                // coalesced
            float v = fminf(xv, r);
            if (v > bv || (v == bv && n < bi)) { bv = v; bi = n; }
        }
        out[BM + b * M + m] = fminf(x[b * N + bi], worig[bi]);   // chosen_w
    } else {
        // ==== phase D: rel_w CDF + ind_x (waves 4-7) ====
        const int b = tid - 256;
        const float tbm = tT[m * B + b];
        float btf = (tbm - wmin) * wscale;
        int kk; double S;
        if (btf < 0.0f) { kk = 0; S = 0.0; }
        else {
            int bt = (int)btf; bt = bt > 255 ? 255 : bt;
            kk = cbase[bt];
            S = (bt > 0) ? bsumI[bt - 1] : 0.0;
            int e = cbase[bt] + cnt[bt];
            for (int i = cbase[bt]; i < e; ++i) {
                float v = wsrt[i];
                if (v < tbm) { ++kk; S += (double)v; }
            }
        }
        double rw = S + (double)tbm * (double)(512 - kk);
        float c = (float)rw / sum_w[m];
        float tgt = fminf(c, pm[511]);
        int lo = 0, hi = 511;
        while (lo < hi) { int mid = (lo + hi) >> 1; if (pm[mid] >= tgt) hi = mid; else lo = mid + 1; }
        const int ind = lo;
        out[b * M + m] = fminf(x[b * N + ind], worig[ind]);      // chosen_x
    }
}

extern "C" void kernel_launch(void* const* d_in, const int* in_sizes, int n_in,
                              void* d_out, int out_size, void* d_ws, size_t ws_size,
                              hipStream_t stream) {
    const float* x = (const float*)d_in[0];  // (B, N)
    const float* w = (const float*)d_in[1];  // (N, M)
    const float* t = (const float*)d_in[2];  // (B, M)
    float* out = (float*)d_out;

    float* ws = (float*)d_ws;
    float* xT    = ws;                 // 131072
    float* wT    = ws + 131072;        // 262144
    float* tT    = ws + 393216;        // 131072
    float* sum_x = ws + 524288;        // 512
    float* sum_w = ws + 524800;        // 512
    float* px    = ws + 525312;        // 4*NM = 1048576  (~6.3 MB total)

    k_a  <<<388, 256, 0, stream>>>(x, w, t, xT, wT, tT, sum_x, sum_w, px);
    k_col<<<512, 512, 0, stream>>>(x, xT, wT, tT, px, sum_x, sum_w, out);
}